// Round 6
// baseline (140.463 us; speedup 1.0000x reference)
//
#include <hip/hip_runtime.h>
#include <hip/hip_bf16.h>
#include <stdint.h>

typedef __attribute__((ext_vector_type(8))) short bf16x8;
typedef __attribute__((ext_vector_type(4))) float f32x4;

#define T_TOKENS 8192
#define DIM 1024
#define ODIM 1024
#define NEXP 8

__device__ __forceinline__ unsigned short f2bf(float f) {
  unsigned u = __float_as_uint(f);
  u = (u + 0x7FFFu + ((u >> 16) & 1u)) >> 16;
  return (unsigned short)u;
}
__device__ __forceinline__ float bf2f(unsigned short h) {
  return __uint_as_float(((unsigned)h) << 16);
}

// ---------------- fused: expert_w fp32->bf16 convert (blocks 0..8191) + router (blocks 8192..10239) ----------------
__global__ __launch_bounds__(256) void prep_kernel(
    const float* __restrict__ ew, unsigned short* __restrict__ w_bf,
    const float* __restrict__ x, const float* __restrict__ gw, const float* __restrict__ gb,
    float* __restrict__ logits_out, unsigned short* __restrict__ x_bf,
    int* __restrict__ tk_e, float* __restrict__ tk_w) {
  if (blockIdx.x < 8192) {
    int i = blockIdx.x * 256 + threadIdx.x;  // 2M float4s
    float4 v = ((const float4*)ew)[i];
    ushort4 o;
    o.x = f2bf(v.x); o.y = f2bf(v.y); o.z = f2bf(v.z); o.w = f2bf(v.w);
    ((ushort4*)w_bf)[i] = o;
    return;
  }
  int wave = threadIdx.x >> 6, lane = threadIdx.x & 63;
  int t = (blockIdx.x - 8192) * 4 + wave;
  float acc[NEXP];
#pragma unroll
  for (int e = 0; e < NEXP; ++e) acc[e] = 0.f;
  const float4* xr = (const float4*)(x + (size_t)t * DIM);
  ushort4* xw = (ushort4*)(x_bf + (size_t)t * DIM);
#pragma unroll
  for (int it = 0; it < 4; ++it) {
    int d4 = it * 64 + lane;
    float4 xv = xr[d4];
    ushort4 xb;
    xb.x = f2bf(xv.x); xb.y = f2bf(xv.y); xb.z = f2bf(xv.z); xb.w = f2bf(xv.w);
    xw[d4] = xb;
#pragma unroll
    for (int e = 0; e < NEXP; ++e) {
      float4 gv = ((const float4*)(gw + e * DIM))[d4];
      acc[e] += xv.x * gv.x + xv.y * gv.y + xv.z * gv.z + xv.w * gv.w;
    }
  }
#pragma unroll
  for (int off = 32; off; off >>= 1)
#pragma unroll
    for (int e = 0; e < NEXP; ++e) acc[e] += __shfl_xor(acc[e], off);
  if (lane == 0) {
#pragma unroll
    for (int e = 0; e < NEXP; ++e) acc[e] += gb[e];
    float4 lo = make_float4(acc[0], acc[1], acc[2], acc[3]);
    float4 hi = make_float4(acc[4], acc[5], acc[6], acc[7]);
    float4* lp = (float4*)(logits_out + (size_t)t * NEXP);
    lp[0] = lo; lp[1] = hi;
    int e0 = 0; float l0 = acc[0];
#pragma unroll
    for (int e = 1; e < NEXP; ++e) if (acc[e] > l0) { l0 = acc[e]; e0 = e; }
    int e1 = -1; float l1 = -1e30f;
#pragma unroll
    for (int e = 0; e < NEXP; ++e) if (e != e0 && acc[e] > l1) { l1 = acc[e]; e1 = e; }
    float r = expf(l1 - l0);          // p1/p0
    float w0 = 1.f / (1.f + r);
    float w1 = r * w0;
    tk_e[t * 2] = e0; tk_e[t * 2 + 1] = e1;
    tk_w[t * 2] = w0; tk_w[t * 2 + 1] = w1;
  }
}

// ---------------- sort: deterministic counting-sort of 16384 (token,k) pairs by expert.
// Emits the XCD-chunked GEMM block schedule: entry = e | (ntile<<4) | (mtile<<8). BM=BN=256.
__global__ __launch_bounds__(1024) void sort_kernel(
    const int* __restrict__ tk_e, const float* __restrict__ tk_w,
    int* __restrict__ offsets_g, int* __restrict__ row_token,
    float* __restrict__ row_weight, int* __restrict__ tk_pos,
    int* __restrict__ tiles_g, int* __restrict__ n_tiles_g) {
  int tid = threadIdx.x;
  int lane = tid & 63, wv = tid >> 6;  // 16 waves
  __shared__ int wavetot[16][NEXP];    // then reused as wave exclusive base
  __shared__ int offs_l[NEXP + 1];

  int pe[16];
  float tw[16];
  const int base = tid * 16;
#pragma unroll
  for (int i = 0; i < 4; ++i) {
    int4 v = ((const int4*)(tk_e + base))[i];
    pe[i * 4 + 0] = v.x; pe[i * 4 + 1] = v.y; pe[i * 4 + 2] = v.z; pe[i * 4 + 3] = v.w;
    float4 w = ((const float4*)(tk_w + base))[i];
    tw[i * 4 + 0] = w.x; tw[i * 4 + 1] = w.y; tw[i * 4 + 2] = w.z; tw[i * 4 + 3] = w.w;
  }
  int h[NEXP];
#pragma unroll
  for (int e = 0; e < NEXP; ++e) h[e] = 0;
#pragma unroll
  for (int i = 0; i < 16; ++i)
#pragma unroll
    for (int e = 0; e < NEXP; ++e) h[e] += (pe[i] == e);

  int incl[NEXP];
#pragma unroll
  for (int e = 0; e < NEXP; ++e) incl[e] = h[e];
#pragma unroll
  for (int off = 1; off < 64; off <<= 1) {
#pragma unroll
    for (int e = 0; e < NEXP; ++e) {
      int n = __shfl_up(incl[e], off);
      if (lane >= off) incl[e] += n;
    }
  }
  if (lane == 63)
#pragma unroll
    for (int e = 0; e < NEXP; ++e) wavetot[wv][e] = incl[e];
  __syncthreads();
  if (tid == 0) {
    int tot[NEXP];
#pragma unroll
    for (int e = 0; e < NEXP; ++e) tot[e] = 0;
    for (int w = 0; w < 16; ++w)
#pragma unroll
      for (int e = 0; e < NEXP; ++e) {
        int v = wavetot[w][e];
        wavetot[w][e] = tot[e];  // exclusive base per wave
        tot[e] += v;
      }
    int o = 0;
#pragma unroll
    for (int e = 0; e < NEXP; ++e) { offs_l[e] = o; o += tot[e]; }
    offs_l[NEXP] = o;
    for (int e = 0; e <= NEXP; ++e) offsets_g[e] = offs_l[e];
    // block schedule: expert-major, m-tile major, n-tile fast (4 n-tiles of 256)
    int nb = 0;
    for (int e = 0; e < NEXP; ++e) {
      int mt = (tot[e] + 255) >> 8;
      for (int m = 0; m < mt; ++m)
        for (int n = 0; n < 4; ++n) tiles_g[nb++] = e | (n << 4) | (m << 8);
    }
    n_tiles_g[0] = nb;
    n_tiles_g[1] = (nb + 7) >> 3;  // chunk size per XCD column
  }
  __syncthreads();

  int mybase[NEXP];
#pragma unroll
  for (int e = 0; e < NEXP; ++e) mybase[e] = offs_l[e] + wavetot[wv][e] + (incl[e] - h[e]);
  int run[NEXP];
#pragma unroll
  for (int e = 0; e < NEXP; ++e) run[e] = 0;
#pragma unroll
  for (int i = 0; i < 16; ++i) {
    int pos = 0;
#pragma unroll
    for (int e = 0; e < NEXP; ++e)
      if (pe[i] == e) { pos = mybase[e] + run[e]; run[e]++; }
    int pair = base + i;
    row_token[pos] = pair >> 1;
    row_weight[pos] = tw[i];
    tk_pos[pair] = pos;
  }
}

// ---------------- grouped GEMM: 256x256 tile, BK=64, 8 waves (2M x 4N), dbuf LDS 128KB,
// m201-style 4-phase/K-tile: {ds_read | prefetch gloads | barrier | lgkmcnt(0) | setprio MFMA | barrier},
// raw vmcnt(0)+s_barrier at K-tile top (loads are >=2 phases old -> near-free drain).
#define GLOAD16(g, l)                                                                   \
  __builtin_amdgcn_global_load_lds((const __attribute__((address_space(1))) unsigned int*)(g), \
                                   (__attribute__((address_space(3))) unsigned int*)(l), 16, 0, 0)

__global__ __launch_bounds__(512, 2) void gemm_kernel(
    const unsigned short* __restrict__ x_bf, const unsigned short* __restrict__ w_bf,
    const int* __restrict__ row_token, const float* __restrict__ row_weight,
    const int* __restrict__ offsets, const int* __restrict__ tiles,
    const int* __restrict__ n_tiles, unsigned short* __restrict__ tmp) {
  int nb = n_tiles[0], cpx = n_tiles[1];
  int wg = blockIdx.x;
  int slot = wg >> 3;
  if (slot >= cpx) return;
  int idx = (wg & 7) * cpx + slot;   // chunked: XCD column gets contiguous schedule run
  if (idx >= nb) return;
  int s = tiles[idx];
  int e = s & 7;
  int n0 = ((s >> 4) & 3) << 8;
  int m0 = (s >> 8) << 8;
  int seg0 = offsets[e], segN = offsets[e + 1] - seg0;

  int tid = threadIdx.x;
  int lane = tid & 63, wave = tid >> 6;
  int wr = wave >> 2, wc = wave & 3;  // 2M x 4N wave grid; wave output 128x64

  // per buffer: A[256][64]bf16 @0 (32KB), B[256][64]bf16 @32768. Buffers @0, @65536.
  __shared__ __align__(16) char smem[131072];

  // ---- staging setup: 8 gloads/K-tile (4 A + 4 B), 64 rows x 128B per gload ----
  const unsigned swz = (unsigned)(((lane & 7) ^ (lane >> 3)) << 4);
  const char* srcA[2][2];
  const char* srcB[2][2];
  int dstA[2][2], dstB[2][2];
#pragma unroll
  for (int hh = 0; hh < 2; ++hh)
#pragma unroll
    for (int i = 0; i < 2; ++i) {
      int rb = hh * 128 + (i * 8 + wave) * 8;   // stripe base row (wave-uniform)
      int rl = rb + (lane >> 3);
      int gr = m0 + rl;
      if (gr > segN - 1) gr = segN - 1;
      int token = row_token[seg0 + gr];
      srcA[hh][i] = (const char*)x_bf + (size_t)token * 2048 + swz;
      srcB[hh][i] = (const char*)w_bf + (((size_t)e << 20) + (size_t)(n0 + rl) * 1024) * 2 + swz;
      dstA[hh][i] = rb * 128;
      dstB[hh][i] = 32768 + rb * 128;
    }

  // ---- ds_read fragment bases (swizzled) ----
  int a_base[2], b_base[2];
#pragma unroll
  for (int ks = 0; ks < 2; ++ks) {
    int kl = ks * 64 + ((lane >> 4) << 4);
    a_base[ks] = wr * 16384 + (lane & 15) * 128 + (kl ^ ((lane & 7) << 4));
    b_base[ks] = 32768 + wc * 8192 + (lane & 15) * 128 + (kl ^ ((lane & 7) << 4));
  }

  f32x4 acc[8][4];
#pragma unroll
  for (int m = 0; m < 8; ++m)
#pragma unroll
    for (int n = 0; n < 4; ++n) acc[m][n] = (f32x4){0.f, 0.f, 0.f, 0.f};

  // ---- prologue: stage K-tile 0 into buf0 (8 gloads) ----
#pragma unroll
  for (int hh = 0; hh < 2; ++hh)
#pragma unroll
    for (int i = 0; i < 2; ++i) GLOAD16(srcA[hh][i], smem + dstA[hh][i]);
#pragma unroll
  for (int hh = 0; hh < 2; ++hh)
#pragma unroll
    for (int i = 0; i < 2; ++i) GLOAD16(srcB[hh][i], smem + dstB[hh][i]);

  // ---- main loop: 16 K-tiles, 4 phases each ----
  for (int kt = 0; kt < 16; ++kt) {
    asm volatile("s_waitcnt vmcnt(0)" ::: "memory");  // tile kt resident (loads >=2 phases old)
    __builtin_amdgcn_s_barrier();
    const int cur = (kt & 1) * 65536;
    const int oth = cur ^ 65536;
    const bool pf = kt < 15;
    const int kbn = (kt + 1) * 128;  // byte offset of next K-tile along K

    bf16x8 b[4][2];
#pragma unroll
    for (int p = 0; p < 4; ++p) {
      // --- ds_read this phase's fragments ---
      if (p == 0) {
#pragma unroll
        for (int n = 0; n < 4; ++n)
#pragma unroll
          for (int ks = 0; ks < 2; ++ks)
            b[n][ks] = *(const bf16x8*)(smem + cur + b_base[ks] + n * 2048);
      }
      bf16x8 a[2][2];
#pragma unroll
      for (int mp = 0; mp < 2; ++mp)
#pragma unroll
        for (int ks = 0; ks < 2; ++ks)
          a[mp][ks] = *(const bf16x8*)(smem + cur + a_base[ks] + (p * 2 + mp) * 2048);

      // --- prefetch next K-tile: A at p0 (3-phase cover), B at p1 (2-phase cover) ---
      if (pf) {
        if (p == 0) {
          GLOAD16(srcA[0][0] + kbn, smem + oth + dstA[0][0]);
          GLOAD16(srcA[0][1] + kbn, smem + oth + dstA[0][1]);
          GLOAD16(srcA[1][0] + kbn, smem + oth + dstA[1][0]);
          GLOAD16(srcA[1][1] + kbn, smem + oth + dstA[1][1]);
        } else if (p == 1) {
          GLOAD16(srcB[0][0] + kbn, smem + oth + dstB[0][0]);
          GLOAD16(srcB[0][1] + kbn, smem + oth + dstB[0][1]);
          GLOAD16(srcB[1][0] + kbn, smem + oth + dstB[1][0]);
          GLOAD16(srcB[1][1] + kbn, smem + oth + dstB[1][1]);
        }
      }

      // --- cluster: all waves' ds_reads done, then MFMA burst ---
      __builtin_amdgcn_s_barrier();
      asm volatile("s_waitcnt lgkmcnt(0)" ::: "memory");
      __builtin_amdgcn_sched_barrier(0);  // rule #18: keep MFMA below the lgkmcnt
      __builtin_amdgcn_s_setprio(1);
#pragma unroll
      for (int mp = 0; mp < 2; ++mp)
#pragma unroll
        for (int ks = 0; ks < 2; ++ks)
#pragma unroll
          for (int n = 0; n < 4; ++n)
            acc[p * 2 + mp][n] =
                __builtin_amdgcn_mfma_f32_16x16x32_bf16(a[mp][ks], b[n][ks], acc[p * 2 + mp][n], 0, 0, 0);
      __builtin_amdgcn_s_setprio(0);
      __builtin_amdgcn_s_barrier();
    }
  }

  // ---- epilogue: scale by routing weight, store bf16 ----
#pragma unroll
  for (int m = 0; m < 8; ++m) {
#pragma unroll
    for (int r = 0; r < 4; ++r) {
      int gr = m0 + wr * 128 + m * 16 + ((lane >> 4) << 2) + r;
      if (gr < segN) {
        int p = seg0 + gr;
        float w = row_weight[p];
#pragma unroll
        for (int n = 0; n < 4; ++n) {
          int col = n0 + wc * 64 + n * 16 + (lane & 15);
          tmp[(size_t)p * 1024 + col] = f2bf(acc[m][n][r] * w);
        }
      }
    }
  }
}

// ---------------- combine: out[t] = tmp[p0] + tmp[p1] + w0*b[e0] + w1*b[e1] ----------------
__global__ __launch_bounds__(256) void combine_kernel(
    const unsigned short* __restrict__ tmp, const float* __restrict__ eb,
    const int* __restrict__ tk_e, const float* __restrict__ tk_w,
    const int* __restrict__ tk_pos, float* __restrict__ out) {
  int t = blockIdx.x;
  int o = threadIdx.x * 4;
  int p0 = tk_pos[t * 2], p1 = tk_pos[t * 2 + 1];
  int e0 = tk_e[t * 2], e1 = tk_e[t * 2 + 1];
  float w0 = tk_w[t * 2], w1 = tk_w[t * 2 + 1];
  ushort4 a = *(const ushort4*)(tmp + (size_t)p0 * 1024 + o);
  ushort4 b = *(const ushort4*)(tmp + (size_t)p1 * 1024 + o);
  float4 b0 = *(const float4*)(eb + e0 * 1024 + o);
  float4 b1 = *(const float4*)(eb + e1 * 1024 + o);
  float4 r;
  r.x = bf2f(a.x) + bf2f(b.x) + w0 * b0.x + w1 * b1.x;
  r.y = bf2f(a.y) + bf2f(b.y) + w0 * b0.y + w1 * b1.y;
  r.z = bf2f(a.z) + bf2f(b.z) + w0 * b0.z + w1 * b1.z;
  r.w = bf2f(a.w) + bf2f(b.w) + w0 * b0.w + w1 * b1.w;
  *(float4*)(out + (size_t)t * 1024 + o) = r;
}

extern "C" void kernel_launch(void* const* d_in, const int* in_sizes, int n_in,
                              void* d_out, int out_size, void* d_ws, size_t ws_size,
                              hipStream_t stream) {
  const float* x  = (const float*)d_in[0];
  const float* gw = (const float*)d_in[1];
  const float* gb = (const float*)d_in[2];
  const float* ew = (const float*)d_in[3];
  const float* eb = (const float*)d_in[4];
  float* out = (float*)d_out;
  float* logits = out + (size_t)T_TOKENS * ODIM;

  char* ws = (char*)d_ws;
  unsigned short* x_bf = (unsigned short*)(ws);                 // 16 MB
  unsigned short* w_bf = (unsigned short*)(ws + 16777216);      // 16 MB
  unsigned short* tmp  = (unsigned short*)(ws + 33554432);      // 32 MB
  int*   tk_e      = (int*)(ws + 67108864);
  float* tk_w      = (float*)(ws + 67174400);
  int*   tk_pos    = (int*)(ws + 67239936);
  int*   row_token = (int*)(ws + 67305472);
  float* row_weight= (float*)(ws + 67371008);
  int*   offsets   = (int*)(ws + 67436544);  // 9 ints
  int*   n_tiles   = (int*)(ws + 67436608);  // 2 ints: nb, cpx
  int*   tiles     = (int*)(ws + 67436672);  // up to 288 ints (block schedule)

  prep_kernel<<<10240, 256, 0, stream>>>(ew, w_bf, x, gw, gb, logits, x_bf, tk_e, tk_w);
  sort_kernel<<<1, 1024, 0, stream>>>(tk_e, tk_w, offsets, row_token, row_weight, tk_pos,
                                      tiles, n_tiles);
  gemm_kernel<<<288, 512, 0, stream>>>(x_bf, w_bf, row_token, row_weight, offsets, tiles,
                                       n_tiles, tmp);
  combine_kernel<<<8192, 256, 0, stream>>>(tmp, eb, tk_e, tk_w, tk_pos, out);
}

// Round 7
// 126.209 us; speedup vs baseline: 1.1129x; 1.1129x over previous
//
#include <hip/hip_runtime.h>
#include <hip/hip_bf16.h>
#include <stdint.h>

typedef __attribute__((ext_vector_type(8))) short bf16x8;
typedef __attribute__((ext_vector_type(4))) float f32x4;

#define T_TOKENS 8192
#define DIM 1024
#define ODIM 1024
#define NEXP 8

__device__ __forceinline__ unsigned short f2bf(float f) {
  unsigned u = __float_as_uint(f);
  u = (u + 0x7FFFu + ((u >> 16) & 1u)) >> 16;
  return (unsigned short)u;
}
__device__ __forceinline__ float bf2f(unsigned short h) {
  return __uint_as_float(((unsigned)h) << 16);
}

// ---------------- router: fp32 logits, top-2, weights; emits x in bf16. NO atomics. ----------------
__global__ __launch_bounds__(256) void router_kernel(
    const float* __restrict__ x, const float* __restrict__ gw, const float* __restrict__ gb,
    float* __restrict__ logits_out, unsigned short* __restrict__ x_bf,
    int* __restrict__ tk_e, float* __restrict__ tk_w) {
  int wave = threadIdx.x >> 6, lane = threadIdx.x & 63;
  int t = blockIdx.x * 4 + wave;
  float acc[NEXP];
#pragma unroll
  for (int e = 0; e < NEXP; ++e) acc[e] = 0.f;
  const float4* xr = (const float4*)(x + (size_t)t * DIM);
  ushort4* xw = (ushort4*)(x_bf + (size_t)t * DIM);
#pragma unroll
  for (int it = 0; it < 4; ++it) {
    int d4 = it * 64 + lane;
    float4 xv = xr[d4];
    ushort4 xb;
    xb.x = f2bf(xv.x); xb.y = f2bf(xv.y); xb.z = f2bf(xv.z); xb.w = f2bf(xv.w);
    xw[d4] = xb;
#pragma unroll
    for (int e = 0; e < NEXP; ++e) {
      float4 gv = ((const float4*)(gw + e * DIM))[d4];
      acc[e] += xv.x * gv.x + xv.y * gv.y + xv.z * gv.z + xv.w * gv.w;
    }
  }
#pragma unroll
  for (int off = 32; off; off >>= 1)
#pragma unroll
    for (int e = 0; e < NEXP; ++e) acc[e] += __shfl_xor(acc[e], off);
  if (lane == 0) {
#pragma unroll
    for (int e = 0; e < NEXP; ++e) acc[e] += gb[e];
    float4 lo = make_float4(acc[0], acc[1], acc[2], acc[3]);
    float4 hi = make_float4(acc[4], acc[5], acc[6], acc[7]);
    float4* lp = (float4*)(logits_out + (size_t)t * NEXP);
    lp[0] = lo; lp[1] = hi;
    int e0 = 0; float l0 = acc[0];
#pragma unroll
    for (int e = 1; e < NEXP; ++e) if (acc[e] > l0) { l0 = acc[e]; e0 = e; }
    int e1 = -1; float l1 = -1e30f;
#pragma unroll
    for (int e = 0; e < NEXP; ++e) if (e != e0 && acc[e] > l1) { l1 = acc[e]; e1 = e; }
    float r = expf(l1 - l0);          // p1/p0
    float w0 = 1.f / (1.f + r);
    float w1 = r * w0;
    tk_e[t * 2] = e0; tk_e[t * 2 + 1] = e1;
    tk_w[t * 2] = w0; tk_w[t * 2 + 1] = w1;
  }
}

// ---------------- fused: block 0 = counting sort + tile schedule; blocks 1..2048 = expert_w convert.
// Sort (1 block, ~7us) hides under the 50MB convert stream.
__global__ __launch_bounds__(1024) void sortconv_kernel(
    const float* __restrict__ ew, unsigned short* __restrict__ w_bf,
    const int* __restrict__ tk_e, const float* __restrict__ tk_w,
    int* __restrict__ offsets_g, int* __restrict__ row_token,
    float* __restrict__ row_weight, int* __restrict__ tk_pos,
    int* __restrict__ tiles_g, int* __restrict__ n_tiles_g) {
  if (blockIdx.x > 0) {
    int i = (blockIdx.x - 1) * 1024 + threadIdx.x;  // 2M float4s
    float4 v = ((const float4*)ew)[i];
    ushort4 o;
    o.x = f2bf(v.x); o.y = f2bf(v.y); o.z = f2bf(v.z); o.w = f2bf(v.w);
    ((ushort4*)w_bf)[i] = o;
    return;
  }
  int tid = threadIdx.x;
  int lane = tid & 63, wv = tid >> 6;  // 16 waves
  __shared__ int wavetot[16][NEXP];    // then reused as wave exclusive base
  __shared__ int offs_l[NEXP + 1];

  int pe[16];
  float tw[16];
  const int base = tid * 16;
#pragma unroll
  for (int i = 0; i < 4; ++i) {
    int4 v = ((const int4*)(tk_e + base))[i];
    pe[i * 4 + 0] = v.x; pe[i * 4 + 1] = v.y; pe[i * 4 + 2] = v.z; pe[i * 4 + 3] = v.w;
    float4 w = ((const float4*)(tk_w + base))[i];
    tw[i * 4 + 0] = w.x; tw[i * 4 + 1] = w.y; tw[i * 4 + 2] = w.z; tw[i * 4 + 3] = w.w;
  }
  int h[NEXP];
#pragma unroll
  for (int e = 0; e < NEXP; ++e) h[e] = 0;
#pragma unroll
  for (int i = 0; i < 16; ++i)
#pragma unroll
    for (int e = 0; e < NEXP; ++e) h[e] += (pe[i] == e);

  int incl[NEXP];
#pragma unroll
  for (int e = 0; e < NEXP; ++e) incl[e] = h[e];
#pragma unroll
  for (int off = 1; off < 64; off <<= 1) {
#pragma unroll
    for (int e = 0; e < NEXP; ++e) {
      int n = __shfl_up(incl[e], off);
      if (lane >= off) incl[e] += n;
    }
  }
  if (lane == 63)
#pragma unroll
    for (int e = 0; e < NEXP; ++e) wavetot[wv][e] = incl[e];
  __syncthreads();
  if (tid == 0) {
    int tot[NEXP];
#pragma unroll
    for (int e = 0; e < NEXP; ++e) tot[e] = 0;
    for (int w = 0; w < 16; ++w)
#pragma unroll
      for (int e = 0; e < NEXP; ++e) {
        int v = wavetot[w][e];
        wavetot[w][e] = tot[e];  // exclusive base per wave
        tot[e] += v;
      }
    int o = 0;
#pragma unroll
    for (int e = 0; e < NEXP; ++e) { offs_l[e] = o; o += tot[e]; }
    offs_l[NEXP] = o;
    for (int e = 0; e <= NEXP; ++e) offsets_g[e] = offs_l[e];
    // block schedule: expert-major, m-tile major, n-tile fast (4 n-tiles of 256)
    int nb = 0;
    for (int e = 0; e < NEXP; ++e) {
      int mt = (tot[e] + 255) >> 8;
      for (int m = 0; m < mt; ++m)
        for (int n = 0; n < 4; ++n) tiles_g[nb++] = e | (n << 4) | (m << 8);
    }
    n_tiles_g[0] = nb;
    n_tiles_g[1] = (nb + 7) >> 3;  // chunk size per XCD column
  }
  __syncthreads();

  int mybase[NEXP];
#pragma unroll
  for (int e = 0; e < NEXP; ++e) mybase[e] = offs_l[e] + wavetot[wv][e] + (incl[e] - h[e]);
  int run[NEXP];
#pragma unroll
  for (int e = 0; e < NEXP; ++e) run[e] = 0;
#pragma unroll
  for (int i = 0; i < 16; ++i) {
    int pos = 0;
#pragma unroll
    for (int e = 0; e < NEXP; ++e)
      if (pe[i] == e) { pos = mybase[e] + run[e]; run[e]++; }
    int pair = base + i;
    row_token[pos] = pair >> 1;
    row_weight[pos] = tw[i];
    tk_pos[pair] = pos;
  }
}

// ---------------- grouped GEMM (R4-proven): 256x256 tile, BK=64, 8 waves, dbuf LDS 128KB,
// 4-phase interleave (JIT ds_read + staged prefetch + setprio MFMA), 1 barrier/K-tile.
#define GLOAD16(g, l)                                                                   \
  __builtin_amdgcn_global_load_lds((const __attribute__((address_space(1))) unsigned int*)(g), \
                                   (__attribute__((address_space(3))) unsigned int*)(l), 16, 0, 0)

__global__ __launch_bounds__(512, 2) void gemm_kernel(
    const unsigned short* __restrict__ x_bf, const unsigned short* __restrict__ w_bf,
    const int* __restrict__ row_token, const float* __restrict__ row_weight,
    const int* __restrict__ offsets, const int* __restrict__ tiles,
    const int* __restrict__ n_tiles, unsigned short* __restrict__ tmp) {
  int nb = n_tiles[0], cpx = n_tiles[1];
  int wg = blockIdx.x;
  int slot = wg >> 3;
  if (slot >= cpx) return;
  int idx = (wg & 7) * cpx + slot;   // chunked: XCD column gets contiguous schedule run
  if (idx >= nb) return;
  int s = tiles[idx];
  int e = s & 7;
  int n0 = ((s >> 4) & 3) << 8;
  int m0 = (s >> 8) << 8;
  int seg0 = offsets[e], segN = offsets[e + 1] - seg0;

  int tid = threadIdx.x;
  int lane = tid & 63, wave = tid >> 6;
  int wr = wave >> 2, wc = wave & 3;  // 2M x 4N wave grid; wave output 128x64

  // per buffer: A[256][64]bf16 @0 (32KB), B[256][64]bf16 @32768. Buffers @0, @65536.
  __shared__ __align__(16) char smem[131072];

  // ---- staging setup: 8 gloads/K-tile (4 A + 4 B), 64 rows x 128B per gload ----
  const unsigned swz = (unsigned)(((lane & 7) ^ (lane >> 3)) << 4);
  const char* srcA[2][2];
  const char* srcB[2][2];
  int dstA[2][2], dstB[2][2];
#pragma unroll
  for (int hh = 0; hh < 2; ++hh)
#pragma unroll
    for (int i = 0; i < 2; ++i) {
      int rb = hh * 128 + (i * 8 + wave) * 8;   // stripe base row (wave-uniform)
      int rl = rb + (lane >> 3);
      int gr = m0 + rl;
      if (gr > segN - 1) gr = segN - 1;
      int token = row_token[seg0 + gr];
      srcA[hh][i] = (const char*)x_bf + (size_t)token * 2048 + swz;
      srcB[hh][i] = (const char*)w_bf + (((size_t)e << 20) + (size_t)(n0 + rl) * 1024) * 2 + swz;
      dstA[hh][i] = rb * 128;
      dstB[hh][i] = 32768 + rb * 128;
    }

  // ---- ds_read fragment bases (swizzled) ----
  int a_base[2], b_base[2];
#pragma unroll
  for (int ks = 0; ks < 2; ++ks) {
    int kl = ks * 64 + ((lane >> 4) << 4);
    a_base[ks] = wr * 16384 + (lane & 15) * 128 + (kl ^ ((lane & 7) << 4));
    b_base[ks] = 32768 + wc * 8192 + (lane & 15) * 128 + (kl ^ ((lane & 7) << 4));
  }

  f32x4 acc[8][4];
#pragma unroll
  for (int m = 0; m < 8; ++m)
#pragma unroll
    for (int n = 0; n < 4; ++n) acc[m][n] = (f32x4){0.f, 0.f, 0.f, 0.f};

  // ---- prologue: stage K-tile 0 into buf0 (8 gloads) ----
#pragma unroll
  for (int hh = 0; hh < 2; ++hh)
#pragma unroll
    for (int i = 0; i < 2; ++i) GLOAD16(srcA[hh][i], smem + dstA[hh][i]);
#pragma unroll
  for (int hh = 0; hh < 2; ++hh)
#pragma unroll
    for (int i = 0; i < 2; ++i) GLOAD16(srcB[hh][i], smem + dstB[hh][i]);

  // ---- main loop: 16 K-tiles, 4 phases each, ONE barrier per K-tile ----
  for (int kt = 0; kt < 16; ++kt) {
    __syncthreads();  // drains vmcnt: tile kt resident in buf[kt&1]; closes reads of kt-1
    const int cur = (kt & 1) * 65536;
    const int oth = cur ^ 65536;
    const bool pf = kt < 15;
    const int kbn = (kt + 1) * 128;  // byte offset of next K-tile along K

    bf16x8 b[4][2];
#pragma unroll
    for (int p = 0; p < 4; ++p) {
      if (p == 0) {
#pragma unroll
        for (int n = 0; n < 4; ++n)
#pragma unroll
          for (int ks = 0; ks < 2; ++ks)
            b[n][ks] = *(const bf16x8*)(smem + cur + b_base[ks] + n * 2048);
      }
      bf16x8 a[2][2];
#pragma unroll
      for (int mp = 0; mp < 2; ++mp)
#pragma unroll
        for (int ks = 0; ks < 2; ++ks)
          a[mp][ks] = *(const bf16x8*)(smem + cur + a_base[ks] + (p * 2 + mp) * 2048);

      if (pf) {
        if (p == 0) {  // A first: gathered rows, need longest cover
          GLOAD16(srcA[0][0] + kbn, smem + oth + dstA[0][0]);
          GLOAD16(srcA[0][1] + kbn, smem + oth + dstA[0][1]);
          GLOAD16(srcA[1][0] + kbn, smem + oth + dstA[1][0]);
          GLOAD16(srcA[1][1] + kbn, smem + oth + dstA[1][1]);
        } else if (p == 1) {
          GLOAD16(srcB[0][0] + kbn, smem + oth + dstB[0][0]);
          GLOAD16(srcB[0][1] + kbn, smem + oth + dstB[0][1]);
        } else if (p == 2) {
          GLOAD16(srcB[1][0] + kbn, smem + oth + dstB[1][0]);
          GLOAD16(srcB[1][1] + kbn, smem + oth + dstB[1][1]);
        }
      }

      __builtin_amdgcn_s_setprio(1);
#pragma unroll
      for (int mp = 0; mp < 2; ++mp)
#pragma unroll
        for (int ks = 0; ks < 2; ++ks)
#pragma unroll
          for (int n = 0; n < 4; ++n)
            acc[p * 2 + mp][n] =
                __builtin_amdgcn_mfma_f32_16x16x32_bf16(a[mp][ks], b[n][ks], acc[p * 2 + mp][n], 0, 0, 0);
      __builtin_amdgcn_s_setprio(0);
    }
  }

  // ---- epilogue: scale by routing weight, store bf16 ----
#pragma unroll
  for (int m = 0; m < 8; ++m) {
#pragma unroll
    for (int r = 0; r < 4; ++r) {
      int gr = m0 + wr * 128 + m * 16 + ((lane >> 4) << 2) + r;
      if (gr < segN) {
        int p = seg0 + gr;
        float w = row_weight[p];
#pragma unroll
        for (int n = 0; n < 4; ++n) {
          int col = n0 + wc * 64 + n * 16 + (lane & 15);
          tmp[(size_t)p * 1024 + col] = f2bf(acc[m][n][r] * w);
        }
      }
    }
  }
}

// ---------------- combine: out[t] = tmp[p0] + tmp[p1] + w0*b[e0] + w1*b[e1] ----------------
__global__ __launch_bounds__(256) void combine_kernel(
    const unsigned short* __restrict__ tmp, const float* __restrict__ eb,
    const int* __restrict__ tk_e, const float* __restrict__ tk_w,
    const int* __restrict__ tk_pos, float* __restrict__ out) {
  int t = blockIdx.x;
  int o = threadIdx.x * 4;
  int p0 = tk_pos[t * 2], p1 = tk_pos[t * 2 + 1];
  int e0 = tk_e[t * 2], e1 = tk_e[t * 2 + 1];
  float w0 = tk_w[t * 2], w1 = tk_w[t * 2 + 1];
  ushort4 a = *(const ushort4*)(tmp + (size_t)p0 * 1024 + o);
  ushort4 b = *(const ushort4*)(tmp + (size_t)p1 * 1024 + o);
  float4 b0 = *(const float4*)(eb + e0 * 1024 + o);
  float4 b1 = *(const float4*)(eb + e1 * 1024 + o);
  float4 r;
  r.x = bf2f(a.x) + bf2f(b.x) + w0 * b0.x + w1 * b1.x;
  r.y = bf2f(a.y) + bf2f(b.y) + w0 * b0.y + w1 * b1.y;
  r.z = bf2f(a.z) + bf2f(b.z) + w0 * b0.z + w1 * b1.z;
  r.w = bf2f(a.w) + bf2f(b.w) + w0 * b0.w + w1 * b1.w;
  *(float4*)(out + (size_t)t * 1024 + o) = r;
}

extern "C" void kernel_launch(void* const* d_in, const int* in_sizes, int n_in,
                              void* d_out, int out_size, void* d_ws, size_t ws_size,
                              hipStream_t stream) {
  const float* x  = (const float*)d_in[0];
  const float* gw = (const float*)d_in[1];
  const float* gb = (const float*)d_in[2];
  const float* ew = (const float*)d_in[3];
  const float* eb = (const float*)d_in[4];
  float* out = (float*)d_out;
  float* logits = out + (size_t)T_TOKENS * ODIM;

  char* ws = (char*)d_ws;
  unsigned short* x_bf = (unsigned short*)(ws);                 // 16 MB
  unsigned short* w_bf = (unsigned short*)(ws + 16777216);      // 16 MB
  unsigned short* tmp  = (unsigned short*)(ws + 33554432);      // 32 MB
  int*   tk_e      = (int*)(ws + 67108864);
  float* tk_w      = (float*)(ws + 67174400);
  int*   tk_pos    = (int*)(ws + 67239936);
  int*   row_token = (int*)(ws + 67305472);
  float* row_weight= (float*)(ws + 67371008);
  int*   offsets   = (int*)(ws + 67436544);  // 9 ints
  int*   n_tiles   = (int*)(ws + 67436608);  // 2 ints: nb, cpx
  int*   tiles     = (int*)(ws + 67436672);  // up to 288 ints (block schedule)

  router_kernel<<<2048, 256, 0, stream>>>(x, gw, gb, logits, x_bf, tk_e, tk_w);
  sortconv_kernel<<<2049, 1024, 0, stream>>>(ew, w_bf, tk_e, tk_w, offsets, row_token,
                                             row_weight, tk_pos, tiles, n_tiles);
  gemm_kernel<<<288, 512, 0, stream>>>(x_bf, w_bf, row_token, row_weight, offsets, tiles,
                                       n_tiles, tmp);
  combine_kernel<<<8192, 256, 0, stream>>>(tmp, eb, tk_e, tk_w, tk_pos, out);
}